// Round 7
// baseline (304.209 us; speedup 1.0000x reference)
//
#include <hip/hip_runtime.h>

// BlockAxialDown: pool2x2 -> axial attn (H)+(W) -> relu -> concat -> 1x1 conv
// -> relu -> batch-stat BN -> NCHW.  B=8 C=128 H2=W2=128 E=256, heads=2 dh=64.
//
// ws (bf16):
//   xp_hw [b][h][w][c], xp_wh [b][w][h][c]  pooled x, both layouts
//   ah [b][w][h][c]  H-attn out (+bias)
//   aw [b][h][w][c]  W-attn out (+bias)
//   yb [b][e][h][w]  pre-BN conv out
// attn: merged dirs, wave=(m,p): q/k/v GEMMs use M=32(2 bands) x N=64(oc half)
// tiles -> halves per-wave LDS B-frag traffic. Weights staged global->LDS.
// conv: wave owns 2 e-tiles, weight frags in regs reused over 8 token-tiles.

typedef short v8s __attribute__((ext_vector_type(8)));
typedef short v4s __attribute__((ext_vector_type(4)));
typedef float v4f __attribute__((ext_vector_type(4)));
typedef float v4flt __attribute__((ext_vector_type(4)));

#define LSA 136   // attn LDS row stride (bf16)
#define LSC 264   // conv LDS row stride
#define LSP 130   // pool LDS row stride

static __device__ __forceinline__ short f2bf(float f){
  unsigned u = __builtin_bit_cast(unsigned, f);
  u = (u + 0x7FFFu + ((u >> 16) & 1u)) >> 16;   // RNE
  return (short)u;
}
static __device__ __forceinline__ float bf2f(short s){
  unsigned u = ((unsigned)(unsigned short)s) << 16;
  return __builtin_bit_cast(float, u);
}

// ---------------- prep: transpose weights to bf16 [out][in]; zero stats ----
__global__ void prep_kernel(const float* __restrict__ Wq_h, const float* __restrict__ Wkv_h,
                            const float* __restrict__ Wout_h, const float* __restrict__ Wq_w,
                            const float* __restrict__ Wkv_w, const float* __restrict__ Wout_w,
                            const float* __restrict__ conv_w, short* __restrict__ wt,
                            float* __restrict__ stats){
  int idx = blockIdx.x * 256 + threadIdx.x;   // 768*256 = 196608 exactly
  if (idx < 8192) stats[idx] = 0.0f;          // 16 copies x 512
  const float* src; int K, O, base;
  if      (idx <  16384){ base = 0;      K=128; O=128; src=Wq_h;  }
  else if (idx <  49152){ base = 16384;  K=128; O=256; src=Wkv_h; }
  else if (idx <  65536){ base = 49152;  K=128; O=128; src=Wout_h;}
  else if (idx <  81920){ base = 65536;  K=128; O=128; src=Wq_w;  }
  else if (idx < 114688){ base = 81920;  K=128; O=256; src=Wkv_w; }
  else if (idx < 131072){ base = 114688; K=128; O=128; src=Wout_w;}
  else                  { base = 131072; K=256; O=256; src=conv_w;}
  int local = idx - base;
  int o = local / K, i = local - o * K;
  wt[idx] = f2bf(src[i * O + o]);   // dst[o][i] = src[i][o]
}

// ---------------- maxpool 2x2 -> bf16, both layouts, LDS transpose --------
__global__ __launch_bounds__(256, 4)
void pool_kernel(const float* __restrict__ x, short* __restrict__ xph,
                 short* __restrict__ xpw){
  __shared__ short t_[128*LSP];     // [j][c]
  int bx = blockIdx.x;              // b*128 + i
  int b = bx >> 7, i = bx & 127;
  int tid = (int)threadIdx.x;
  int j2 = tid & 63;                // lane handles output cols 2*j2, 2*j2+1
  int cq = tid >> 6;                // 4 channel groups
  for (int rep = 0; rep < 32; ++rep){
    int c = cq*32 + rep;
    const float* p0 = x + (((b*128 + c)*256 + 2*i)*256 + 4*j2);
    v4flt a  = *(const v4flt*)p0;          // 16B coalesced
    v4flt bb = *(const v4flt*)(p0 + 256);
    t_[(2*j2)*LSP + c]   = f2bf(fmaxf(fmaxf(a[0], a[1]), fmaxf(bb[0], bb[1])));
    t_[(2*j2+1)*LSP + c] = f2bf(fmaxf(fmaxf(a[2], a[3]), fmaxf(bb[2], bb[3])));
  }
  __syncthreads();
  int obase_h = ((b*128 + i)*128)*128;         // xph[b][i][j][c]
  for (int rep = 0; rep < 8; ++rep){
    int idx = rep*256 + tid;                   // 2048 v8s total
    int row = idx >> 4, seg = idx & 15;        // row=j, seg*8=c
    v8s v = *(const v8s*)(&t_[row*LSP + seg*8]);
    *(v8s*)(xph + obase_h + row*128 + seg*8) = v;
    *(v8s*)(xpw + ((b*128 + row)*128 + i)*128 + seg*8) = v;  // xpw[b][j][i][c]
  }
}

// ---------------- fused axial attention, merged dirs ----------------------
// 2048 blocks: dir = bx&1. One (b,s) per 512-thr block, 8 waves.
// Weight GEMMs (q,k,v): wave (m = w>>1, p = w&1) computes token rows
// [32m,32m+32) x oc [64p,64p+64) -> per-wave B-frag LDS reads halved.
// S^T/softmax/O^T/out-proj: per 16-band w (unchanged).
__global__ __launch_bounds__(512, 4)
void attn_kernel(const short* __restrict__ xp_hw, const short* __restrict__ xp_wh,
                 const short* __restrict__ wt,
                 const float* __restrict__ bout_h, const float* __restrict__ bout_w,
                 short* __restrict__ ah, short* __restrict__ aw){
  __shared__ short A[128*LSA];      // 34,816 B
  __shared__ short WB[128*LSA];     // 34,816 B

  const int bx = blockIdx.x;
  const int dir = bx & 1;
  const int sb = bx >> 1;
  const int b = sb >> 7, s = sb & 127;
  const int tid = (int)threadIdx.x;
  const int w = tid >> 6;
  const int m = w >> 1;             // 32-row band pair
  const int p = w & 1;              // 64-col oc half
  const int lane = tid & 63;
  const int l15 = lane & 15, l4 = lane >> 4;

  const short* Wq   = wt + dir*65536;     // [oc][ic] 128x128 each
  const short* Wk   = Wq + 16384;
  const short* Wv   = Wq + 32768;
  const short* Wout = Wq + 49152;
  const float* bsrc = dir ? bout_w : bout_h;
  const short* xsrc = dir ? xp_hw : xp_wh;
  short*       ao   = dir ? aw : ah;

  // x A-frags for 2 bands (rows 32m+16ti+l15), contiguous tile
  v8s av[2][4];
  #pragma unroll
  for (int ti = 0; ti < 2; ++ti){
    int xbase = ((b*128 + s)*128 + (32*m + 16*ti + l15))*128;
    #pragma unroll
    for (int kk = 0; kk < 4; ++kk)
      av[ti][kk] = *(const v8s*)(xsrc + xbase + kk*32 + l4*8);
  }

  // stage macro: 128x128 bf16 matrix global -> WB (stride LSA)
#define STAGE_W(SRC)                                                     \
  { _Pragma("unroll")                                                    \
    for (int r_ = 0; r_ < 4; ++r_){                                      \
      int idx_ = (r_*512 + tid) * 8;                                     \
      int oc_ = idx_ >> 7, ic_ = idx_ & 127;                             \
      *(v8s*)(&WB[oc_*LSA + ic_]) = *(const v8s*)((SRC) + idx_);         \
    } }

  // M32xN64 weight-GEMM macro: out to A[t][oc]
#define WGEMM_TO_A()                                                     \
  { _Pragma("unroll")                                                    \
    for (int ti = 0; ti < 2; ++ti){                                      \
      _Pragma("unroll")                                                  \
      for (int tc = 0; tc < 4; ++tc){                                    \
        int ocb = 64*p + 16*tc;                                          \
        v4f d = {0.f,0.f,0.f,0.f};                                       \
        _Pragma("unroll")                                                \
        for (int kk = 0; kk < 4; ++kk){                                  \
          v8s bf = *(const v8s*)(&WB[(ocb + l15)*LSA + kk*32 + l4*8]);   \
          d = __builtin_amdgcn_mfma_f32_16x16x32_bf16(av[ti][kk], bf, d, 0, 0, 0); \
        }                                                                \
        _Pragma("unroll")                                                \
        for (int r = 0; r < 4; ++r)                                      \
          A[(32*m + 16*ti + 4*l4 + r)*LSA + ocb + l15] = f2bf(d[r]);     \
      } } }

  STAGE_W(Wq);
  __syncthreads();                  // B1: Wq staged

  WGEMM_TO_A();                     // q -> A (cross-wave tiles)
  __syncthreads();                  // B2: q visible + Wq reads done

  // bq readback (own 16-band) while staging Wk
  v8s bq[2][2];
  #pragma unroll
  for (int h = 0; h < 2; ++h)
    #pragma unroll
    for (int kk = 0; kk < 2; ++kk)
      bq[h][kk] = *(const v8s*)(&A[(16*w + l15)*LSA + h*64 + kk*32 + l4*8]);
  STAGE_W(Wk);
  __syncthreads();                  // B3: Wk staged + bq reads done (A free)

  WGEMM_TO_A();                     // k -> A
  __syncthreads();                  // B4: k visible + Wk reads done

  STAGE_W(Wv);                      // ds_writes overlap S^T below

  // ---- S^T = K.Q^T per head + softmax; P packed in regs (band w) ----
  v4s pk[2][8];
  #pragma unroll
  for (int h = 0; h < 2; ++h){
    v4f st[8];
    #pragma unroll
    for (int jt = 0; jt < 8; ++jt){
      v4f d = {0.f,0.f,0.f,0.f};
      #pragma unroll
      for (int kk = 0; kk < 2; ++kk){
        v8s ak = *(const v8s*)(&A[(16*jt + l15)*LSA + h*64 + kk*32 + l4*8]);
        d = __builtin_amdgcn_mfma_f32_16x16x32_bf16(ak, bq[h][kk], d, 0, 0, 0);
      }
      st[jt] = d;
    }
    float mx = -1e30f;
    #pragma unroll
    for (int jt = 0; jt < 8; ++jt)
      #pragma unroll
      for (int r = 0; r < 4; ++r) mx = fmaxf(mx, st[jt][r]);
    mx = fmaxf(mx, __shfl_xor(mx, 16));
    mx = fmaxf(mx, __shfl_xor(mx, 32));
    float sm = 0.f;
    #pragma unroll
    for (int jt = 0; jt < 8; ++jt)
      #pragma unroll
      for (int r = 0; r < 4; ++r){
        float e = __expf((st[jt][r] - mx) * 0.125f);   // * dh^-0.5
        st[jt][r] = e; sm += e;
      }
    sm += __shfl_xor(sm, 16);
    sm += __shfl_xor(sm, 32);
    float inv = 1.0f / sm;
    #pragma unroll
    for (int jt = 0; jt < 8; ++jt)
      #pragma unroll
      for (int r = 0; r < 4; ++r) pk[h][jt][r] = f2bf(st[jt][r] * inv);
  }
  __syncthreads();                  // B5: k reads done (A free); Wv staged

  // ---- P -> own band A; readback pa (per head, wave-local) ----
  v8s pa[2][4];
  #pragma unroll
  for (int h = 0; h < 2; ++h){
    #pragma unroll
    for (int jt = 0; jt < 8; ++jt)
      *(v4s*)(&A[(16*w + l15)*LSA + 16*jt + 4*l4]) = pk[h][jt];
    #pragma unroll
    for (int kk = 0; kk < 4; ++kk)
      pa[h][kk] = *(const v8s*)(&A[(16*w + l15)*LSA + kk*32 + l4*8]);
  }
  __syncthreads();                  // B6: all pa read-backs done (A free)

  // ---- v = x @ Wv -> v^T in A [ch][tok] (M32xN64 tiles, v4s writes) ----
  #pragma unroll
  for (int ti = 0; ti < 2; ++ti){
    #pragma unroll
    for (int tc = 0; tc < 4; ++tc){
      int ocb = 64*p + 16*tc;
      v4f d = {0.f,0.f,0.f,0.f};
      #pragma unroll
      for (int kk = 0; kk < 4; ++kk){
        v8s bf = *(const v8s*)(&WB[(ocb + l15)*LSA + kk*32 + l4*8]);
        d = __builtin_amdgcn_mfma_f32_16x16x32_bf16(av[ti][kk], bf, d, 0, 0, 0);
      }
      v4s pkv;
      #pragma unroll
      for (int r = 0; r < 4; ++r) pkv[r] = f2bf(d[r]);
      *(v4s*)(&A[(ocb + l15)*LSA + 32*m + 16*ti + 4*l4]) = pkv;
    }
  }
  __syncthreads();                  // B7: v^T visible + Wv reads done

  STAGE_W(Wout);                    // overlap with O^T below

  // ---- O^T = V^T . P^T : A-frags from A(v^T), B = pa (band w) ----
  v4f ot[2][4];
  #pragma unroll
  for (int h = 0; h < 2; ++h)
    #pragma unroll
    for (int tc = 0; tc < 4; ++tc){
      v4f d = {0.f,0.f,0.f,0.f};
      #pragma unroll
      for (int kk = 0; kk < 4; ++kk){
        v8s vf = *(const v8s*)(&A[(64*h + 16*tc + l15)*LSA + kk*32 + l4*8]);
        d = __builtin_amdgcn_mfma_f32_16x16x32_bf16(vf, pa[h][kk], d, 0, 0, 0);
      }
      ot[h][tc] = d;
    }
  __syncthreads();                  // B8: v^T reads done; Wout staged

  // ---- O -> own band A [i][d]; ob; out-proj; Z -> own band ----
  #pragma unroll
  for (int h = 0; h < 2; ++h)
    #pragma unroll
    for (int tc = 0; tc < 4; ++tc){
      v4s pko;
      #pragma unroll
      for (int r = 0; r < 4; ++r) pko[r] = f2bf(ot[h][tc][r]);
      *(v4s*)(&A[(16*w + l15)*LSA + 64*h + 16*tc + 4*l4]) = pko;
    }
  v8s ob[4];
  #pragma unroll
  for (int kk = 0; kk < 4; ++kk)
    ob[kk] = *(const v8s*)(&A[(16*w + l15)*LSA + kk*32 + l4*8]);
  #pragma unroll
  for (int tc = 0; tc < 8; ++tc){
    v4f d = {0.f,0.f,0.f,0.f};
    #pragma unroll
    for (int kk = 0; kk < 4; ++kk){
      v8s awf = *(const v8s*)(&WB[(tc*16 + l15)*LSA + kk*32 + l4*8]);
      d = __builtin_amdgcn_mfma_f32_16x16x32_bf16(awf, ob[kk], d, 0, 0, 0);
    }
    v4f bias = *(const v4f*)(bsrc + 16*tc + 4*l4);
    v4s z;
    #pragma unroll
    for (int r = 0; r < 4; ++r) z[r] = f2bf(d[r] + bias[r]);
    *(v4s*)(&A[(16*w + l15)*LSA + 16*tc + 4*l4]) = z;   // Z[i][oc], own band
  }
  __syncthreads();                  // B9: Z tile complete

  int obase = ((b*128 + s)*128)*128;
  #pragma unroll
  for (int r = 0; r < 4; ++r){
    int idx = (r*512 + tid) * 8;
    int t = idx >> 7, c = idx & 127;
    *(v8s*)(ao + obase + t*128 + c) = *(const v8s*)(&A[t*LSA + c]);
  }
#undef STAGE_W
#undef WGEMM_TO_A
}

// ---------------- concat + 1x1 conv + relu + bf16 y + stats ---------------
__global__ __launch_bounds__(512, 2)
void conv_kernel(const short* __restrict__ ah, const short* __restrict__ aw,
                 const short* __restrict__ xp, const short* __restrict__ wt,
                 short* __restrict__ yb, float* __restrict__ stats){
  __shared__ short cats[128*LSC];   // staged [t][256]; reused as y [256][132]
  __shared__ float lsum[256];
  __shared__ float lsq[256];
  const short* convT = wt + 131072; // [e][f] bf16
  int bx = blockIdx.x;              // b*128 + ii (image h-row; tokens j = w)
  int b = bx >> 7, ii = bx & 127;
  int tid = (int)threadIdx.x;
  int wv = tid >> 6, lane = tid & 63, l15 = lane & 15, l4 = lane >> 4;
  if (tid < 256){ lsum[tid] = 0.f; lsq[tid] = 0.f; }

  // weight frags for this wave's two e-tiles (issued first, reused 8x)
  v8s wf[2][8];
  #pragma unroll
  for (int x = 0; x < 2; ++x)
    #pragma unroll
    for (int kk = 0; kk < 8; ++kk)
      wf[x][kk] = *(const v8s*)(convT + (((wv + 8*x)*16 + l15)*256) + kk*32 + l4*8);

  // stage cat = [relu(ah+aw) | xp]
  for (int r = 0; r < 4; ++r){
    int idx = (r*512 + tid) * 8;
    int t = idx >> 7, c = idx & 127;
    v8s hv = *(const v8s*)(ah + ((b*128 + t)*128 + ii)*128 + c);
    v8s wv_ = *(const v8s*)(aw + ((b*128 + ii)*128 + t)*128 + c);
    v8s o;
    #pragma unroll
    for (int k = 0; k < 8; ++k)
      o[k] = f2bf(fmaxf(bf2f(hv[k]) + bf2f(wv_[k]), 0.f));
    *(v8s*)(&cats[t*LSC + c]) = o;
    *(v8s*)(&cats[t*LSC + 128 + c]) =
        *(const v8s*)(xp + ((b*128 + ii)*128 + t)*128 + c);
  }
  __syncthreads();

  v4s ypk[2][8];                    // packed y tiles [x][tt]
  float s1[2] = {0.f,0.f}, s2[2] = {0.f,0.f};
  #pragma unroll
  for (int tt = 0; tt < 8; ++tt){
    v4f d0 = {0.f,0.f,0.f,0.f}, d1 = {0.f,0.f,0.f,0.f};
    #pragma unroll
    for (int kk = 0; kk < 8; ++kk){
      v8s af = *(const v8s*)(&cats[(16*tt + l15)*LSC + kk*32 + l4*8]);
      d0 = __builtin_amdgcn_mfma_f32_16x16x32_bf16(af, wf[0][kk], d0, 0, 0, 0);
      d1 = __builtin_amdgcn_mfma_f32_16x16x32_bf16(af, wf[1][kk], d1, 0, 0, 0);
    }
    #pragma unroll
    for (int r = 0; r < 4; ++r){
      float y0 = fmaxf(d0[r], 0.f), y1 = fmaxf(d1[r], 0.f);
      ypk[0][tt][r] = f2bf(y0); ypk[1][tt][r] = f2bf(y1);
      s1[0] += y0; s2[0] += y0*y0;
      s1[1] += y1; s2[1] += y1*y1;
    }
  }
  #pragma unroll
  for (int x = 0; x < 2; ++x){
    s1[x] += __shfl_xor(s1[x], 16); s1[x] += __shfl_xor(s1[x], 32);
    s2[x] += __shfl_xor(s2[x], 16); s2[x] += __shfl_xor(s2[x], 32);
  }
  if (l4 == 0){
    #pragma unroll
    for (int x = 0; x < 2; ++x){
      int e = (wv + 8*x)*16 + l15;
      atomicAdd(&lsum[e], s1[x]);
      atomicAdd(&lsq[e],  s2[x]);
    }
  }
  __syncthreads();                  // all cat reads done; reuse as y [256][132]
  #pragma unroll
  for (int x = 0; x < 2; ++x)
    #pragma unroll
    for (int tt = 0; tt < 8; ++tt)
      *(v4s*)(&cats[((wv + 8*x)*16 + l15)*132 + 16*tt + 4*l4]) = ypk[x][tt];
  __syncthreads();
  for (int r = 0; r < 8; ++r){      // coalesced bf16 y store [b][e][ii][j]
    int idx = (r*512 + tid) * 8;
    int e = idx >> 7, j = idx & 127;
    *(v8s*)(yb + ((b*256 + e)*128 + ii)*128 + j) = *(const v8s*)(&cats[e*132 + j]);
  }
  if (tid < 256){
    int c = bx & 15;                // 16-way spread
    atomicAdd(&stats[c*512 + tid],       lsum[tid]);
    atomicAdd(&stats[c*512 + 256 + tid], lsq[tid]);
  }
}

// ---------------- BN: bf16 y -> fp32 out, block = one (b,e) plane ---------
__global__ void bn_kernel(const short* __restrict__ yb, float* __restrict__ out,
                          const float* __restrict__ stats,
                          const float* __restrict__ gamma, const float* __restrict__ beta){
  const float invn = 1.0f / 131072.0f;
  int bx = blockIdx.x;              // b*256 + e
  int e = bx & 255;
  float s1 = 0.f, s2 = 0.f;
  #pragma unroll
  for (int c = 0; c < 16; ++c){
    s1 += stats[c*512 + e];
    s2 += stats[c*512 + 256 + e];
  }
  float m   = s1 * invn;
  float var = s2 * invn - m * m;
  float sc  = gamma[e] * rsqrtf(var + 1e-5f);
  float sh  = beta[e] - m * sc;
  int base = bx * 16384;
  int tid = (int)threadIdx.x;       // 256
  for (int rep = 0; rep < 8; ++rep){
    int idx = base + (rep*256 + tid)*8;
    v8s yv = *(const v8s*)(yb + idx);
    v4f o1, o2;
    #pragma unroll
    for (int r = 0; r < 4; ++r){
      o1[r] = bf2f(yv[r])   * sc + sh;
      o2[r] = bf2f(yv[4+r]) * sc + sh;
    }
    *(v4f*)(out + idx)     = o1;
    *(v4f*)(out + idx + 4) = o2;
  }
}

extern "C" void kernel_launch(void* const* d_in, const int* in_sizes, int n_in,
                              void* d_out, int out_size, void* d_ws, size_t ws_size,
                              hipStream_t stream){
  const float* x      = (const float*)d_in[0];
  const float* Wq_h   = (const float*)d_in[1];
  const float* Wkv_h  = (const float*)d_in[2];
  const float* Wout_h = (const float*)d_in[3];
  const float* bout_h = (const float*)d_in[4];
  const float* Wq_w   = (const float*)d_in[5];
  const float* Wkv_w  = (const float*)d_in[6];
  const float* Wout_w = (const float*)d_in[7];
  const float* bout_w = (const float*)d_in[8];
  const float* conv_w = (const float*)d_in[9];
  const float* gamma  = (const float*)d_in[10];
  const float* beta   = (const float*)d_in[11];
  float* out = (float*)d_out;

  char* ws = (char*)d_ws;
  short* xp_hw = (short*)(ws);               // [0, 33554432)            bf16 [b][h][w][c]
  short* xp_wh = (short*)(ws +  33554432);   // [33554432, 67108864)     bf16 [b][w][h][c]
  short* ah    = (short*)(ws +  67108864);   // [67108864, 100663296)    bf16 [b][w][h][c]
  short* aw    = (short*)(ws + 100663296);   // [100663296, 134217728)   bf16 [b][h][w][c]
  short* yb    = (short*)(ws + 134217728);   // [134217728, 201326592)   bf16 [b][e][h][w]
  short* wt    = (short*)(ws + 201326592);   // [201326592, 201719808)   bf16 W^T pack
  float* stats = (float*)(ws + 201719808);   // [201719808, 201752576)   BN sums x16

  prep_kernel<<<768, 256, 0, stream>>>(Wq_h, Wkv_h, Wout_h, Wq_w, Wkv_w, Wout_w,
                                       conv_w, wt, stats);
  pool_kernel<<<1024, 256, 0, stream>>>(x, xp_hw, xp_wh);
  attn_kernel<<<2048, 512, 0, stream>>>(xp_hw, xp_wh, wt, bout_h, bout_w, ah, aw);
  conv_kernel<<<1024, 512, 0, stream>>>(ah, aw, xp_hw, wt, yb, stats);
  bn_kernel<<<2048, 256, 0, stream>>>(yb, out, stats, gamma, beta);
}

// Round 8
// 285.484 us; speedup vs baseline: 1.0656x; 1.0656x over previous
//
#include <hip/hip_runtime.h>

// BlockAxialDown: pool2x2 -> axial attn (H)+(W) -> relu -> concat -> 1x1 conv
// -> relu -> batch-stat BN -> NCHW.  B=8 C=128 H2=W2=128 E=256, heads=2 dh=64.
//
// ws (bf16):
//   xp_hw [b][h][w][c], xp_wh [b][w][h][c]  pooled x, both layouts
//   ah [b][w][h][c]  H-attn out (+bias)
//   aw [b][h][w][c]  W-attn out (+bias)
//   yb [b][e][h][w]  pre-BN conv out
// attn: 1024-thr block = TWO s-problems sharing one staged weight buffer
//   (halves staging + barrier overhead per problem). Wave-local M16xN128 GEMMs.
// conv: wave owns 2 e-tiles, weight frags in regs reused over 8 token-tiles.

typedef short v8s __attribute__((ext_vector_type(8)));
typedef short v4s __attribute__((ext_vector_type(4)));
typedef float v4f __attribute__((ext_vector_type(4)));
typedef float v4flt __attribute__((ext_vector_type(4)));

#define LSA 136   // attn LDS row stride (bf16)
#define LSC 264   // conv LDS row stride
#define LSP 130   // pool LDS row stride

static __device__ __forceinline__ short f2bf(float f){
  unsigned u = __builtin_bit_cast(unsigned, f);
  u = (u + 0x7FFFu + ((u >> 16) & 1u)) >> 16;   // RNE
  return (short)u;
}
static __device__ __forceinline__ float bf2f(short s){
  unsigned u = ((unsigned)(unsigned short)s) << 16;
  return __builtin_bit_cast(float, u);
}

// ---------------- prep: transpose weights to bf16 [out][in]; zero stats ----
__global__ void prep_kernel(const float* __restrict__ Wq_h, const float* __restrict__ Wkv_h,
                            const float* __restrict__ Wout_h, const float* __restrict__ Wq_w,
                            const float* __restrict__ Wkv_w, const float* __restrict__ Wout_w,
                            const float* __restrict__ conv_w, short* __restrict__ wt,
                            float* __restrict__ stats){
  int idx = blockIdx.x * 256 + threadIdx.x;   // 768*256 = 196608 exactly
  if (idx < 8192) stats[idx] = 0.0f;          // 16 copies x 512
  const float* src; int K, O, base;
  if      (idx <  16384){ base = 0;      K=128; O=128; src=Wq_h;  }
  else if (idx <  49152){ base = 16384;  K=128; O=256; src=Wkv_h; }
  else if (idx <  65536){ base = 49152;  K=128; O=128; src=Wout_h;}
  else if (idx <  81920){ base = 65536;  K=128; O=128; src=Wq_w;  }
  else if (idx < 114688){ base = 81920;  K=128; O=256; src=Wkv_w; }
  else if (idx < 131072){ base = 114688; K=128; O=128; src=Wout_w;}
  else                  { base = 131072; K=256; O=256; src=conv_w;}
  int local = idx - base;
  int o = local / K, i = local - o * K;
  wt[idx] = f2bf(src[i * O + o]);   // dst[o][i] = src[i][o]
}

// ---------------- maxpool 2x2 -> bf16, both layouts, LDS transpose --------
__global__ __launch_bounds__(256, 4)
void pool_kernel(const float* __restrict__ x, short* __restrict__ xph,
                 short* __restrict__ xpw){
  __shared__ short t_[128*LSP];     // [j][c]
  int bx = blockIdx.x;              // b*128 + i
  int b = bx >> 7, i = bx & 127;
  int tid = (int)threadIdx.x;
  int j2 = tid & 63;                // lane handles output cols 2*j2, 2*j2+1
  int cq = tid >> 6;                // 4 channel groups
  for (int rep = 0; rep < 32; ++rep){
    int c = cq*32 + rep;
    const float* p0 = x + (((b*128 + c)*256 + 2*i)*256 + 4*j2);
    v4flt a  = *(const v4flt*)p0;          // 16B coalesced
    v4flt bb = *(const v4flt*)(p0 + 256);
    t_[(2*j2)*LSP + c]   = f2bf(fmaxf(fmaxf(a[0], a[1]), fmaxf(bb[0], bb[1])));
    t_[(2*j2+1)*LSP + c] = f2bf(fmaxf(fmaxf(a[2], a[3]), fmaxf(bb[2], bb[3])));
  }
  __syncthreads();
  int obase_h = ((b*128 + i)*128)*128;         // xph[b][i][j][c]
  for (int rep = 0; rep < 8; ++rep){
    int idx = rep*256 + tid;                   // 2048 v8s total
    int row = idx >> 4, seg = idx & 15;        // row=j, seg*8=c
    v8s v = *(const v8s*)(&t_[row*LSP + seg*8]);
    *(v8s*)(xph + obase_h + row*128 + seg*8) = v;
    *(v8s*)(xpw + ((b*128 + row)*128 + i)*128 + seg*8) = v;  // xpw[b][j][i][c]
  }
}

// ---------------- fused axial attention: 2 problems / 1024-thr block ------
// 1024 blocks: dir = bx&1, (b, s-pair) = bx>>1. Waves 0-7 -> s0, 8-15 -> s1.
// One shared WB staging serves both problems (staging/barrier cost halved).
// Per problem: wave = 16-token band, M16xN128 wave-local GEMMs (R5 form).
__global__ __launch_bounds__(1024, 4)
void attn_kernel(const short* __restrict__ xp_hw, const short* __restrict__ xp_wh,
                 const short* __restrict__ wt,
                 const float* __restrict__ bout_h, const float* __restrict__ bout_w,
                 short* __restrict__ ah, short* __restrict__ aw){
  __shared__ short A2[2][128*LSA];  // 69,632 B (one work buffer per problem)
  __shared__ short WB[128*LSA];     // 34,816 B (shared staged weights)

  const int bx = blockIdx.x;
  const int dir = bx & 1;
  const int sb = bx >> 1;           // [0,512)
  const int b = sb >> 6, sp = sb & 63;
  const int tid = (int)threadIdx.x;
  const int prob = tid >> 9;        // 0 or 1
  const int ptid = tid & 511;
  const int w = ptid >> 6;          // wave-in-problem 0..7 (16-token band)
  const int lane = tid & 63;
  const int l15 = lane & 15, l4 = lane >> 4;
  const int s = sp*2 + prob;

  short* A = &A2[prob][0];

  const short* Wq   = wt + dir*65536;     // [oc][ic] 128x128 each
  const short* Wk   = Wq + 16384;
  const short* Wv   = Wq + 32768;
  const short* Wout = Wq + 49152;
  const float* bsrc = dir ? bout_w : bout_h;
  const short* xsrc = dir ? xp_hw : xp_wh;
  short*       ao   = dir ? aw : ah;

  // x A-frags: contiguous 32KB tile per problem, 4 loads (full lines)
  const int trow = 16*w + l15;
  const int xbase = ((b*128 + s)*128 + trow)*128;
  v8s av[4];
  #pragma unroll
  for (int kk = 0; kk < 4; ++kk)
    av[kk] = *(const v8s*)(xsrc + xbase + kk*32 + l4*8);

  // stage macro: 128x128 bf16 matrix global -> WB; 1024 threads, 2 v8s each
#define STAGE_W(SRC)                                                     \
  { _Pragma("unroll")                                                    \
    for (int r_ = 0; r_ < 2; ++r_){                                      \
      int idx_ = (r_*1024 + tid) * 8;                                    \
      int oc_ = idx_ >> 7, ic_ = idx_ & 127;                             \
      *(v8s*)(&WB[oc_*LSA + ic_]) = *(const v8s*)((SRC) + idx_);         \
    } }

  STAGE_W(Wq);
  __syncthreads();                  // B1: Wq staged

  // ---- q = x @ Wq -> own band A [t][c]; wave-local bq readback ----
  #pragma unroll
  for (int tc = 0; tc < 8; ++tc){
    v4f d = {0.f,0.f,0.f,0.f};
    #pragma unroll
    for (int kk = 0; kk < 4; ++kk){
      v8s bf = *(const v8s*)(&WB[(tc*16 + l15)*LSA + kk*32 + l4*8]);
      d = __builtin_amdgcn_mfma_f32_16x16x32_bf16(av[kk], bf, d, 0, 0, 0);
    }
    #pragma unroll
    for (int r = 0; r < 4; ++r)
      A[(16*w + 4*l4 + r)*LSA + 16*tc + l15] = f2bf(d[r]);
  }
  v8s bq[2][2];
  #pragma unroll
  for (int h = 0; h < 2; ++h)
    #pragma unroll
    for (int kk = 0; kk < 2; ++kk)
      bq[h][kk] = *(const v8s*)(&A[(16*w + l15)*LSA + h*64 + kk*32 + l4*8]);
  __syncthreads();                  // B2: Wq reads done

  STAGE_W(Wk);
  __syncthreads();                  // B3: Wk staged

  // ---- k = x @ Wk -> own band A [t][c] ----
  #pragma unroll
  for (int tc = 0; tc < 8; ++tc){
    v4f d = {0.f,0.f,0.f,0.f};
    #pragma unroll
    for (int kk = 0; kk < 4; ++kk){
      v8s bf = *(const v8s*)(&WB[(tc*16 + l15)*LSA + kk*32 + l4*8]);
      d = __builtin_amdgcn_mfma_f32_16x16x32_bf16(av[kk], bf, d, 0, 0, 0);
    }
    #pragma unroll
    for (int r = 0; r < 4; ++r)
      A[(16*w + 4*l4 + r)*LSA + 16*tc + l15] = f2bf(d[r]);
  }
  __syncthreads();                  // B4: k visible + Wk reads done

  STAGE_W(Wv);                      // ds_writes overlap S^T below

  // ---- S^T = K.Q^T per head + softmax; P packed in regs ----
  v4s pk[2][8];
  #pragma unroll
  for (int h = 0; h < 2; ++h){
    v4f st[8];
    #pragma unroll
    for (int jt = 0; jt < 8; ++jt){
      v4f d = {0.f,0.f,0.f,0.f};
      #pragma unroll
      for (int kk = 0; kk < 2; ++kk){
        v8s ak = *(const v8s*)(&A[(16*jt + l15)*LSA + h*64 + kk*32 + l4*8]);
        d = __builtin_amdgcn_mfma_f32_16x16x32_bf16(ak, bq[h][kk], d, 0, 0, 0);
      }
      st[jt] = d;
    }
    float mx = -1e30f;
    #pragma unroll
    for (int jt = 0; jt < 8; ++jt)
      #pragma unroll
      for (int r = 0; r < 4; ++r) mx = fmaxf(mx, st[jt][r]);
    mx = fmaxf(mx, __shfl_xor(mx, 16));
    mx = fmaxf(mx, __shfl_xor(mx, 32));
    float sm = 0.f;
    #pragma unroll
    for (int jt = 0; jt < 8; ++jt)
      #pragma unroll
      for (int r = 0; r < 4; ++r){
        float e = __expf((st[jt][r] - mx) * 0.125f);   // * dh^-0.5
        st[jt][r] = e; sm += e;
      }
    sm += __shfl_xor(sm, 16);
    sm += __shfl_xor(sm, 32);
    float inv = 1.0f / sm;
    #pragma unroll
    for (int jt = 0; jt < 8; ++jt)
      #pragma unroll
      for (int r = 0; r < 4; ++r) pk[h][jt][r] = f2bf(st[jt][r] * inv);
  }
  __syncthreads();                  // B5: k reads done (A free); Wv staged

  // ---- P -> own band A; readback pa (per head, wave-local) ----
  v8s pa[2][4];
  #pragma unroll
  for (int h = 0; h < 2; ++h){
    #pragma unroll
    for (int jt = 0; jt < 8; ++jt)
      *(v4s*)(&A[(16*w + l15)*LSA + 16*jt + 4*l4]) = pk[h][jt];
    #pragma unroll
    for (int kk = 0; kk < 4; ++kk)
      pa[h][kk] = *(const v8s*)(&A[(16*w + l15)*LSA + kk*32 + l4*8]);
  }
  __syncthreads();                  // B6: all pa read-backs done (A free)

  // ---- v = x @ Wv -> v^T in A [ch][tok] (v4s writes, own token cols) ----
  #pragma unroll
  for (int tc = 0; tc < 8; ++tc){
    v4f d = {0.f,0.f,0.f,0.f};
    #pragma unroll
    for (int kk = 0; kk < 4; ++kk){
      v8s bf = *(const v8s*)(&WB[(tc*16 + l15)*LSA + kk*32 + l4*8]);
      d = __builtin_amdgcn_mfma_f32_16x16x32_bf16(av[kk], bf, d, 0, 0, 0);
    }
    v4s pkv;
    #pragma unroll
    for (int r = 0; r < 4; ++r) pkv[r] = f2bf(d[r]);
    *(v4s*)(&A[(16*tc + l15)*LSA + 16*w + 4*l4]) = pkv;
  }
  __syncthreads();                  // B7: v^T visible + Wv reads done

  STAGE_W(Wout);                    // overlap with O^T below

  // ---- O^T = V^T . P^T : A-frags from A(v^T), B = pa ----
  v4f ot[2][4];
  #pragma unroll
  for (int h = 0; h < 2; ++h)
    #pragma unroll
    for (int tc = 0; tc < 4; ++tc){
      v4f d = {0.f,0.f,0.f,0.f};
      #pragma unroll
      for (int kk = 0; kk < 4; ++kk){
        v8s vf = *(const v8s*)(&A[(64*h + 16*tc + l15)*LSA + kk*32 + l4*8]);
        d = __builtin_amdgcn_mfma_f32_16x16x32_bf16(vf, pa[h][kk], d, 0, 0, 0);
      }
      ot[h][tc] = d;
    }
  __syncthreads();                  // B8: v^T reads done; Wout staged

  // ---- O -> own band A [i][d]; ob; out-proj; Z -> own band ----
  #pragma unroll
  for (int h = 0; h < 2; ++h)
    #pragma unroll
    for (int tc = 0; tc < 4; ++tc){
      v4s pko;
      #pragma unroll
      for (int r = 0; r < 4; ++r) pko[r] = f2bf(ot[h][tc][r]);
      *(v4s*)(&A[(16*w + l15)*LSA + 64*h + 16*tc + 4*l4]) = pko;
    }
  v8s ob[4];
  #pragma unroll
  for (int kk = 0; kk < 4; ++kk)
    ob[kk] = *(const v8s*)(&A[(16*w + l15)*LSA + kk*32 + l4*8]);
  #pragma unroll
  for (int tc = 0; tc < 8; ++tc){
    v4f d = {0.f,0.f,0.f,0.f};
    #pragma unroll
    for (int kk = 0; kk < 4; ++kk){
      v8s awf = *(const v8s*)(&WB[(tc*16 + l15)*LSA + kk*32 + l4*8]);
      d = __builtin_amdgcn_mfma_f32_16x16x32_bf16(awf, ob[kk], d, 0, 0, 0);
    }
    v4f bias = *(const v4f*)(bsrc + 16*tc + 4*l4);
    v4s z;
    #pragma unroll
    for (int r = 0; r < 4; ++r) z[r] = f2bf(d[r] + bias[r]);
    *(v4s*)(&A[(16*w + l15)*LSA + 16*tc + 4*l4]) = z;   // Z[i][oc], own band
  }
  __syncthreads();                  // B9: Z tiles complete

  // ---- coalesced store of this problem's [128][128] tile ----
  int obase = ((b*128 + s)*128)*128;
  #pragma unroll
  for (int r = 0; r < 4; ++r){
    int idx = (r*512 + ptid) * 8;
    int t = idx >> 7, c = idx & 127;
    *(v8s*)(ao + obase + t*128 + c) = *(const v8s*)(&A[t*LSA + c]);
  }
#undef STAGE_W
}

// ---------------- concat + 1x1 conv + relu + bf16 y + stats ---------------
__global__ __launch_bounds__(512, 2)
void conv_kernel(const short* __restrict__ ah, const short* __restrict__ aw,
                 const short* __restrict__ xp, const short* __restrict__ wt,
                 short* __restrict__ yb, float* __restrict__ stats){
  __shared__ short cats[128*LSC];   // staged [t][256]; reused as y [256][132]
  __shared__ float lsum[256];
  __shared__ float lsq[256];
  const short* convT = wt + 131072; // [e][f] bf16
  int bx = blockIdx.x;              // b*128 + ii (image h-row; tokens j = w)
  int b = bx >> 7, ii = bx & 127;
  int tid = (int)threadIdx.x;
  int wv = tid >> 6, lane = tid & 63, l15 = lane & 15, l4 = lane >> 4;
  if (tid < 256){ lsum[tid] = 0.f; lsq[tid] = 0.f; }

  // weight frags for this wave's two e-tiles (issued first, reused 8x)
  v8s wf[2][8];
  #pragma unroll
  for (int x = 0; x < 2; ++x)
    #pragma unroll
    for (int kk = 0; kk < 8; ++kk)
      wf[x][kk] = *(const v8s*)(convT + (((wv + 8*x)*16 + l15)*256) + kk*32 + l4*8);

  // stage cat = [relu(ah+aw) | xp]
  for (int r = 0; r < 4; ++r){
    int idx = (r*512 + tid) * 8;
    int t = idx >> 7, c = idx & 127;
    v8s hv = *(const v8s*)(ah + ((b*128 + t)*128 + ii)*128 + c);
    v8s wv_ = *(const v8s*)(aw + ((b*128 + ii)*128 + t)*128 + c);
    v8s o;
    #pragma unroll
    for (int k = 0; k < 8; ++k)
      o[k] = f2bf(fmaxf(bf2f(hv[k]) + bf2f(wv_[k]), 0.f));
    *(v8s*)(&cats[t*LSC + c]) = o;
    *(v8s*)(&cats[t*LSC + 128 + c]) =
        *(const v8s*)(xp + ((b*128 + ii)*128 + t)*128 + c);
  }
  __syncthreads();

  v4s ypk[2][8];                    // packed y tiles [x][tt]
  float s1[2] = {0.f,0.f}, s2[2] = {0.f,0.f};
  #pragma unroll
  for (int tt = 0; tt < 8; ++tt){
    v4f d0 = {0.f,0.f,0.f,0.f}, d1 = {0.f,0.f,0.f,0.f};
    #pragma unroll
    for (int kk = 0; kk < 8; ++kk){
      v8s af = *(const v8s*)(&cats[(16*tt + l15)*LSC + kk*32 + l4*8]);
      d0 = __builtin_amdgcn_mfma_f32_16x16x32_bf16(af, wf[0][kk], d0, 0, 0, 0);
      d1 = __builtin_amdgcn_mfma_f32_16x16x32_bf16(af, wf[1][kk], d1, 0, 0, 0);
    }
    #pragma unroll
    for (int r = 0; r < 4; ++r){
      float y0 = fmaxf(d0[r], 0.f), y1 = fmaxf(d1[r], 0.f);
      ypk[0][tt][r] = f2bf(y0); ypk[1][tt][r] = f2bf(y1);
      s1[0] += y0; s2[0] += y0*y0;
      s1[1] += y1; s2[1] += y1*y1;
    }
  }
  #pragma unroll
  for (int x = 0; x < 2; ++x){
    s1[x] += __shfl_xor(s1[x], 16); s1[x] += __shfl_xor(s1[x], 32);
    s2[x] += __shfl_xor(s2[x], 16); s2[x] += __shfl_xor(s2[x], 32);
  }
  if (l4 == 0){
    #pragma unroll
    for (int x = 0; x < 2; ++x){
      int e = (wv + 8*x)*16 + l15;
      atomicAdd(&lsum[e], s1[x]);
      atomicAdd(&lsq[e],  s2[x]);
    }
  }
  __syncthreads();                  // all cat reads done; reuse as y [256][132]
  #pragma unroll
  for (int x = 0; x < 2; ++x)
    #pragma unroll
    for (int tt = 0; tt < 8; ++tt)
      *(v4s*)(&cats[((wv + 8*x)*16 + l15)*132 + 16*tt + 4*l4]) = ypk[x][tt];
  __syncthreads();
  for (int r = 0; r < 8; ++r){      // coalesced bf16 y store [b][e][ii][j]
    int idx = (r*512 + tid) * 8;
    int e = idx >> 7, j = idx & 127;
    *(v8s*)(yb + ((b*256 + e)*128 + ii)*128 + j) = *(const v8s*)(&cats[e*132 + j]);
  }
  if (tid < 256){
    int c = bx & 15;                // 16-way spread
    atomicAdd(&stats[c*512 + tid],       lsum[tid]);
    atomicAdd(&stats[c*512 + 256 + tid], lsq[tid]);
  }
}

// ---------------- BN: bf16 y -> fp32 out, block = one (b,e) plane ---------
__global__ void bn_kernel(const short* __restrict__ yb, float* __restrict__ out,
                          const float* __restrict__ stats,
                          const float* __restrict__ gamma, const float* __restrict__ beta){
  const float invn = 1.0f / 131072.0f;
  int bx = blockIdx.x;              // b*256 + e
  int e = bx & 255;
  float s1 = 0.f, s2 = 0.f;
  #pragma unroll
  for (int c = 0; c < 16; ++c){
    s1 += stats[c*512 + e];
    s2 += stats[c*512 + 256 + e];
  }
  float m   = s1 * invn;
  float var = s2 * invn - m * m;
  float sc  = gamma[e] * rsqrtf(var + 1e-5f);
  float sh  = beta[e] - m * sc;
  int base = bx * 16384;
  int tid = (int)threadIdx.x;       // 256
  for (int rep = 0; rep < 8; ++rep){
    int idx = base + (rep*256 + tid)*8;
    v8s yv = *(const v8s*)(yb + idx);
    v4f o1, o2;
    #pragma unroll
    for (int r = 0; r < 4; ++r){
      o1[r] = bf2f(yv[r])   * sc + sh;
      o2[r] = bf2f(yv[4+r]) * sc + sh;
    }
    *(v4f*)(out + idx)     = o1;
    *(v4f*)(out + idx + 4) = o2;
  }
}

extern "C" void kernel_launch(void* const* d_in, const int* in_sizes, int n_in,
                              void* d_out, int out_size, void* d_ws, size_t ws_size,
                              hipStream_t stream){
  const float* x      = (const float*)d_in[0];
  const float* Wq_h   = (const float*)d_in[1];
  const float* Wkv_h  = (const float*)d_in[2];
  const float* Wout_h = (const float*)d_in[3];
  const float* bout_h = (const float*)d_in[4];
  const float* Wq_w   = (const float*)d_in[5];
  const float* Wkv_w  = (const float*)d_in[6];
  const float* Wout_w = (const float*)d_in[7];
  const float* bout_w = (const float*)d_in[8];
  const float* conv_w = (const float*)d_in[9];
  const float* gamma  = (const float*)d_in[10];
  const float* beta   = (const float*)d_in[11];
  float* out = (float*)d_out;

  char* ws = (char*)d_ws;
  short* xp_hw = (short*)(ws);               // [0, 33554432)            bf16 [b][h][w][c]
  short* xp_wh = (short*)(ws +  33554432);   // [33554432, 67108864)     bf16 [b][w][h][c]
  short* ah    = (short*)(ws +  67108864);   // [67108864, 100663296)    bf16 [b][w][h][c]
  short* aw    = (short*)(ws + 100663296);   // [100663296, 134217728)   bf16 [b][h][w][c]
  short* yb    = (short*)(ws + 134217728);   // [134217728, 201326592)   bf16 [b][e][h][w]
  short* wt    = (short*)(ws + 201326592);   // [201326592, 201719808)   bf16 W^T pack
  float* stats = (float*)(ws + 201719808);   // [201719808, 201752576)   BN sums x16

  prep_kernel<<<768, 256, 0, stream>>>(Wq_h, Wkv_h, Wout_h, Wq_w, Wkv_w, Wout_w,
                                       conv_w, wt, stats);
  pool_kernel<<<1024, 256, 0, stream>>>(x, xp_hw, xp_wh);
  attn_kernel<<<1024, 1024, 0, stream>>>(xp_hw, xp_wh, wt, bout_h, bout_w, ah, aw);
  conv_kernel<<<1024, 512, 0, stream>>>(ah, aw, xp_hw, wt, yb, stats);
  bn_kernel<<<2048, 256, 0, stream>>>(yb, out, stats, gamma, beta);
}